// Round 2
// 191.634 us; speedup vs baseline: 1.0016x; 1.0016x over previous
//
#include <hip/hip_runtime.h>
#include <math.h>

#define HIDDEN  512
#define EXPERTS 4
#define QUAD    4

// One wave (64 lanes) per token-quad. Lane l covers x positions {l*4..l*4+3}
// and {256+l*4..256+l*4+3}. Gate fragments live in registers across the
// grid-stride loop (gate_w is only 4x512 floats).
//
// Reduction: pack 4 expert partials -> 1 value/lane in 3 shuffles
// (lane l ends owning expert l&3), then 4 butterfly stages + 3 broadcast
// shuffles = 10 shuffles/token (was 24). Four tokens are processed per
// iteration so the four dependent shuffle chains interleave (ILP) and the
// 8 float4 global loads are all in flight together.
__global__ __launch_bounds__(256, 4) void gating_kernel(
    const float* __restrict__ x,        // [T, 512]
    const float* __restrict__ gate_w,   // [4, 512]
    const float* __restrict__ gate_b,   // [4]
    float* __restrict__ out_sparse,     // [T, 4]
    float* __restrict__ out_idx,        // [T, 2]  (indices stored as float)
    float* __restrict__ out_logit,      // [T, 4]
    int T)
{
    const int lane   = threadIdx.x & 63;
    const int wave   = (int)((blockIdx.x * blockDim.x + threadIdx.x) >> 6);
    const int nwaves = (int)((gridDim.x * blockDim.x) >> 6);

    // Per-lane gate fragments: 4 experts x 8 floats = 32 VGPRs. Loaded once.
    float4 gw0[EXPERTS], gw1[EXPERTS];
#pragma unroll
    for (int e = 0; e < EXPERTS; ++e) {
        gw0[e] = *reinterpret_cast<const float4*>(gate_w + e * HIDDEN + lane * 4);
        gw1[e] = *reinterpret_cast<const float4*>(gate_w + e * HIDDEN + 256 + lane * 4);
    }
    const float b0 = gate_b[0], b1 = gate_b[1], b2 = gate_b[2], b3 = gate_b[3];
    const int id = lane & 3;

    const int nquads = T >> 2;

    for (int q = wave; q < nquads; q += nwaves) {
        const int t0 = q * 4;

        // ---- issue all 8 loads (4 tokens x 2KB, fully coalesced) ----
        float4 xv0[QUAD], xv1[QUAD];
#pragma unroll
        for (int j = 0; j < QUAD; ++j) {
            const float* xt = x + (size_t)(t0 + j) * HIDDEN;
            xv0[j] = *reinterpret_cast<const float4*>(xt + lane * 4);
            xv1[j] = *reinterpret_cast<const float4*>(xt + 256 + lane * 4);
        }

        // ---- per-lane partial dot products ----
        float s[QUAD][EXPERTS];
#pragma unroll
        for (int j = 0; j < QUAD; ++j) {
#pragma unroll
            for (int e = 0; e < EXPERTS; ++e) {
                s[j][e] = xv0[j].x * gw0[e].x + xv0[j].y * gw0[e].y
                        + xv0[j].z * gw0[e].z + xv0[j].w * gw0[e].w
                        + xv1[j].x * gw1[e].x + xv1[j].y * gw1[e].y
                        + xv1[j].z * gw1[e].z + xv1[j].w * gw1[e].w;
            }
        }

        // ---- pack stage 1 (xor 1): even lanes keep experts {0,2}, odd {1,3} ----
        float u[QUAD], v[QUAD];
#pragma unroll
        for (int j = 0; j < QUAD; ++j) {
            float snd = (lane & 1) ? s[j][0] : s[j][1];
            float rcv = __shfl_xor(snd, 1, 64);
            u[j] = ((lane & 1) ? s[j][1] : s[j][0]) + rcv;
        }
#pragma unroll
        for (int j = 0; j < QUAD; ++j) {
            float snd = (lane & 1) ? s[j][2] : s[j][3];
            float rcv = __shfl_xor(snd, 1, 64);
            v[j] = ((lane & 1) ? s[j][3] : s[j][2]) + rcv;
        }

        // ---- pack stage 2 (xor 2): lane l now owns expert (l&3) over its 4-lane group ----
        float r[QUAD];
#pragma unroll
        for (int j = 0; j < QUAD; ++j) {
            float snd = (lane & 2) ? u[j] : v[j];
            float rcv = __shfl_xor(snd, 2, 64);
            r[j] = ((lane & 2) ? v[j] : u[j]) + rcv;
        }

        // ---- butterfly across groups: expert (l&3) total in every lane of its class ----
#pragma unroll
        for (int j = 0; j < QUAD; ++j) r[j] += __shfl_xor(r[j], 4, 64);
#pragma unroll
        for (int j = 0; j < QUAD; ++j) r[j] += __shfl_xor(r[j], 8, 64);
#pragma unroll
        for (int j = 0; j < QUAD; ++j) r[j] += __shfl_xor(r[j], 16, 64);
#pragma unroll
        for (int j = 0; j < QUAD; ++j) r[j] += __shfl_xor(r[j], 32, 64);

        // ---- broadcast: gather the other three expert totals ----
        float ga[QUAD], gb[QUAD], gc[QUAD];
#pragma unroll
        for (int j = 0; j < QUAD; ++j) ga[j] = __shfl_xor(r[j], 1, 64);   // expert id^1
#pragma unroll
        for (int j = 0; j < QUAD; ++j) gb[j] = __shfl_xor(r[j], 2, 64);   // expert id^2
#pragma unroll
        for (int j = 0; j < QUAD; ++j) gc[j] = __shfl_xor(ga[j], 2, 64);  // expert id^3

        // ---- per-token: reorder, top-2, softmax, store ----
#pragma unroll
        for (int j = 0; j < QUAD; ++j) {
            // value with m = e ^ id: 0->r, 1->ga, 2->gb, 3->gc  (wave-uniform result)
            float l_[4];
#pragma unroll
            for (int e = 0; e < 4; ++e) {
                const int m = e ^ id;
                const float t01 = (m & 1) ? ga[j] : r[j];
                const float t23 = (m & 1) ? gc[j] : gb[j];
                l_[e] = (m & 2) ? t23 : t01;
            }
            l_[0] += b0; l_[1] += b1; l_[2] += b2; l_[3] += b3;

            // top-1: strict > keeps the lowest index on ties (matches lax.top_k)
            int i1 = 0; float m1 = l_[0];
#pragma unroll
            for (int e = 1; e < 4; ++e) { if (l_[e] > m1) { m1 = l_[e]; i1 = e; } }
            int i2 = -1; float m2 = -INFINITY;
#pragma unroll
            for (int e = 0; e < 4; ++e) { if (e != i1 && l_[e] > m2) { m2 = l_[e]; i2 = e; } }

            const float e2  = expf(m2 - m1);
            const float inv = 1.0f / (1.0f + e2);
            const float p1  = inv, p2 = e2 * inv;

            if (lane == 0) {
                float sp[4];
#pragma unroll
                for (int e = 0; e < 4; ++e)
                    sp[e] = (e == i1) ? p1 : ((e == i2) ? p2 : 0.0f);
                const int t = t0 + j;
                *reinterpret_cast<float4*>(out_sparse + (size_t)t * 4) =
                    make_float4(sp[0], sp[1], sp[2], sp[3]);
                *reinterpret_cast<float2*>(out_idx + (size_t)t * 2) =
                    make_float2((float)i1, (float)i2);
                *reinterpret_cast<float4*>(out_logit + (size_t)t * 4) =
                    make_float4(l_[0], l_[1], l_[2], l_[3]);
            }
        }
    }

    // ---- tail: T not a multiple of 4 (not hit for T=65536, kept for generality) ----
    for (int t = (nquads << 2) + wave; t < T; t += nwaves) {
        const float* xt = x + (size_t)t * HIDDEN;
        const float4 xa = *reinterpret_cast<const float4*>(xt + lane * 4);
        const float4 xb = *reinterpret_cast<const float4*>(xt + 256 + lane * 4);
        float s[EXPERTS];
#pragma unroll
        for (int e = 0; e < EXPERTS; ++e) {
            s[e] = xa.x * gw0[e].x + xa.y * gw0[e].y + xa.z * gw0[e].z + xa.w * gw0[e].w
                 + xb.x * gw1[e].x + xb.y * gw1[e].y + xb.z * gw1[e].z + xb.w * gw1[e].w;
        }
#pragma unroll
        for (int off = 32; off >= 1; off >>= 1) {
#pragma unroll
            for (int e = 0; e < EXPERTS; ++e) s[e] += __shfl_xor(s[e], off, 64);
        }
        const float l_[4] = {s[0] + b0, s[1] + b1, s[2] + b2, s[3] + b3};
        int i1 = 0; float m1 = l_[0];
#pragma unroll
        for (int e = 1; e < 4; ++e) { if (l_[e] > m1) { m1 = l_[e]; i1 = e; } }
        int i2 = -1; float m2 = -INFINITY;
#pragma unroll
        for (int e = 0; e < 4; ++e) { if (e != i1 && l_[e] > m2) { m2 = l_[e]; i2 = e; } }
        const float e2  = expf(m2 - m1);
        const float inv = 1.0f / (1.0f + e2);
        const float p1  = inv, p2 = e2 * inv;
        if (lane == 0) {
            float sp[4];
#pragma unroll
            for (int e = 0; e < 4; ++e)
                sp[e] = (e == i1) ? p1 : ((e == i2) ? p2 : 0.0f);
            *reinterpret_cast<float4*>(out_sparse + (size_t)t * 4) =
                make_float4(sp[0], sp[1], sp[2], sp[3]);
            *reinterpret_cast<float2*>(out_idx + (size_t)t * 2) =
                make_float2((float)i1, (float)i2);
            *reinterpret_cast<float4*>(out_logit + (size_t)t * 4) =
                make_float4(l_[0], l_[1], l_[2], l_[3]);
        }
    }
}

extern "C" void kernel_launch(void* const* d_in, const int* in_sizes, int n_in,
                              void* d_out, int out_size, void* d_ws, size_t ws_size,
                              hipStream_t stream) {
    const float* x      = (const float*)d_in[0];
    const float* gate_w = (const float*)d_in[1];
    const float* gate_b = (const float*)d_in[2];

    const int T = in_sizes[0] / HIDDEN;   // 65536 for B=8, S=8192

    float* out_sparse = (float*)d_out;                       // T*4
    float* out_idx    = out_sparse + (size_t)T * EXPERTS;    // T*2
    float* out_logit  = out_idx    + (size_t)T * 2;          // T*4

    const dim3 block(256);
    const dim3 grid(1024);   // 4096 waves -> 4 quads (16 tokens) per wave
    gating_kernel<<<grid, block, 0, stream>>>(x, gate_w, gate_b,
                                              out_sparse, out_idx, out_logit, T);
}